// Round 7
// baseline (1221.230 us; speedup 1.0000x reference)
//
#include <hip/hip_runtime.h>
#include <math.h>

#define B_ 256
#define N_ 200
#define D_ 128
#define H_ 8
#define KD_ 16
#define L_ 3
#define FF_ 512
#define ROWS (B_*N_)          // 51200
#define BND (ROWS*D_)         // 6,553,600

typedef __bf16 bf16x8 __attribute__((ext_vector_type(8)));
typedef float f32x4 __attribute__((ext_vector_type(4)));
typedef float f32x2 __attribute__((ext_vector_type(2)));

__device__ __forceinline__ ushort f2bf(float f) {
  union { float f; unsigned u; } v; v.f = f;
  unsigned r = v.u + 0x7fffu + ((v.u >> 16) & 1u);
  return (ushort)(r >> 16);
}
__device__ __forceinline__ float bf2f(ushort h) {
  union { unsigned u; float f; } v; v.u = ((unsigned)h) << 16; return v.f;
}
__device__ __forceinline__ void split2(float f, ushort& hi, ushort& lo) {
  hi = f2bf(f);
  lo = f2bf(f - bf2f(hi));
}

// ---------------- embed: h = x @ Wemb + bemb -> hp fp32 + hi/lo bf16 ----------------
__global__ __launch_bounds__(256) void embed_kernel(const float* __restrict__ x,
    const float* __restrict__ Wemb, const float* __restrict__ bemb,
    float* __restrict__ hp, ushort* __restrict__ hhi, ushort* __restrict__ hlo)
{
  int i4 = blockIdx.x * 256 + threadIdx.x;   // ROWS*32 float4s
  int r  = i4 >> 5, c4 = i4 & 31;
  float x0 = x[2*r], x1 = x[2*r + 1];
  const float4 w0 = ((const float4*)Wemb)[c4];
  const float4 w1 = ((const float4*)Wemb)[32 + c4];
  const float4 bb = ((const float4*)bemb)[c4];
  float o[4];
  o[0] = fmaf(x0, w0.x, fmaf(x1, w1.x, bb.x));
  o[1] = fmaf(x0, w0.y, fmaf(x1, w1.y, bb.y));
  o[2] = fmaf(x0, w0.z, fmaf(x1, w1.z, bb.z));
  o[3] = fmaf(x0, w0.w, fmaf(x1, w1.w, bb.w));
  float4 of = { o[0], o[1], o[2], o[3] };
  ((float4*)hp)[i4] = of;
  ushort hi[4], lo[4];
#pragma unroll
  for (int k = 0; k < 4; k++) split2(o[k], hi[k], lo[k]);
  uint2 ph, pl;
  ph.x = (uint)hi[0] | ((uint)hi[1] << 16);
  ph.y = (uint)hi[2] | ((uint)hi[3] << 16);
  pl.x = (uint)lo[0] | ((uint)lo[1] << 16);
  pl.y = (uint)lo[2] | ((uint)lo[3] << 16);
  ((uint2*)hhi)[i4] = ph;
  ((uint2*)hlo)[i4] = pl;
}

// ------------- static weight transposes (Wo, W2) -> bf16 hi/lo [N][K] -------------
__global__ __launch_bounds__(256) void t_wo(const float* __restrict__ Wo,
    ushort* __restrict__ dhi, ushort* __restrict__ dlo)
{
  int i = blockIdx.x * 256 + threadIdx.x;     // L*128*128 = 49152 exact
  int l = i / 16384, r = i % 16384;
  int n = r >> 7, k = r & 127;
  int hh = k >> 4, kd = k & 15;
  float w = Wo[l*16384 + hh*2048 + kd*128 + n];
  split2(w, dhi[i], dlo[i]);
}
__global__ __launch_bounds__(256) void t_w2(const float* __restrict__ W2,
    ushort* __restrict__ dhi, ushort* __restrict__ dlo)
{
  int i = blockIdx.x * 256 + threadIdx.x;     // L*128*512 = 196608 exact
  int l = i / 65536, r = i % 65536;
  int d = r >> 9, f = r & 511;
  float w = W2[l*65536 + f*128 + d];
  split2(w, dhi[i], dlo[i]);
}

// ------------- init BN-fold state to identity -------------
__global__ __launch_bounds__(128) void init_scales(float* __restrict__ sc, float* __restrict__ sh)
{
  int c = threadIdx.x;
  sc[c] = 1.f;
  sh[c] = 0.f;
}

// ------------- fold BN into QKV weights: W' = diag(sc)@Wqkv, b' = sh@Wqkv -------------
__global__ __launch_bounds__(384) void fold_qkv(const float* __restrict__ Wq,
    const float* __restrict__ Wk, const float* __restrict__ Wv,
    const float* __restrict__ sc, const float* __restrict__ sh,
    ushort* __restrict__ whi, ushort* __restrict__ wlo, float* __restrict__ bout)
{
  int n = threadIdx.x;                    // 0..383
  int which = n >> 7, hh = (n >> 4) & 7, kd = n & 15;
  const float* src = (which == 0) ? Wq : (which == 1) ? Wk : Wv;
  src += hh*2048 + kd;
  float bacc = 0.f;
  for (int k = 0; k < 128; k++) {
    float w = src[k*16];
    split2(w * sc[k], whi[n*128 + k], wlo[n*128 + k]);
    bacc = fmaf(sh[k], w, bacc);
  }
  bout[n] = bacc;
}

// ------------- fold BN into W1: W1' = diag(sc)@W1, b1' = b1 + sh@W1 -------------
__global__ __launch_bounds__(256) void fold_w1(const float* __restrict__ W1,
    const float* __restrict__ b1, const float* __restrict__ sc, const float* __restrict__ sh,
    ushort* __restrict__ whi, ushort* __restrict__ wlo, float* __restrict__ bout)
{
  int f = blockIdx.x * 256 + threadIdx.x; // 0..511
  float bacc = b1[f];
  for (int k = 0; k < 128; k++) {
    float w = W1[k*512 + f];
    split2(w * sc[k], whi[f*128 + k], wlo[f*128 + k]);
    bacc = fmaf(sh[k], w, bacc);
  }
  bout[f] = bacc;
}

// ---------------- split-bf16 MFMA GEMM: R3 body (BK=64, XOR swizzle) + BN-fold epilogue ----------------
// A, W as bf16 hi/lo, K-major. C = Ahi@Whi + Alo@Whi + Ahi@Wlo (+bias)(relu).
// RESIDBN: C += residf*rsc[col]+rsh[col]. OUTF32 -> Cf; OUTHL -> hi/lo split;
// STATS: per-block column sum/sumsq -> psum/psq[blockIdx.y*128+c] (gridDim.x==1).
template<int K, bool BIAS, bool RELU, bool RESIDBN, bool OUTF32, bool OUTHL, bool STATS>
__global__ __launch_bounds__(256, 2) void gemm_mfma(
    const ushort* __restrict__ Ahi, const ushort* __restrict__ Alo,
    const ushort* __restrict__ Whi, const ushort* __restrict__ Wlo,
    const float* __restrict__ bias,
    const float* __restrict__ residf, const float* __restrict__ rsc, const float* __restrict__ rsh,
    float* __restrict__ Cf, ushort* __restrict__ Chi, ushort* __restrict__ Clo,
    float* __restrict__ psum, float* __restrict__ psq, int Ntot)
{
  __shared__ ushort AhiS[128*64];
  __shared__ ushort AloS[128*64];
  __shared__ ushort BhiS[128*64];
  __shared__ ushort BloS[128*64];
  const int t    = threadIdx.x;
  const int bm   = blockIdx.y * 128;
  const int bn   = blockIdx.x * 128;
  const int lane = t & 63;
  const int w    = t >> 6, wm = w >> 1, wn = w & 1;
  const int quad = lane >> 4, l15 = lane & 15;

  f32x4 acc[4][4];
#pragma unroll
  for (int i = 0; i < 4; i++)
#pragma unroll
    for (int j = 0; j < 4; j++) acc[i][j] = (f32x4){0.f, 0.f, 0.f, 0.f};

  const ushort* AhiB = Ahi + (size_t)bm * K;
  const ushort* AloB = Alo + (size_t)bm * K;
  const ushort* BhiB = Whi + (size_t)bn * K;
  const ushort* BloB = Wlo + (size_t)bn * K;

  for (int k0 = 0; k0 < K; k0 += 64) {
    // stage 128 rows x 64 k; LDS [row][c], c = k8 ^ (row&7) (XOR swizzle)
#pragma unroll
    for (int i = 0; i < 4; i++) {
      int idx = i * 256 + t;
      int row = idx >> 3, c = idx & 7;
      int k8  = c ^ (row & 7);
      size_t off = (size_t)row * K + k0 + k8 * 8;
      ((uint4*)AhiS)[idx] = *(const uint4*)(AhiB + off);
      ((uint4*)AloS)[idx] = *(const uint4*)(AloB + off);
      ((uint4*)BhiS)[idx] = *(const uint4*)(BhiB + off);
      ((uint4*)BloS)[idx] = *(const uint4*)(BloB + off);
    }
    __syncthreads();
#pragma unroll
    for (int ks = 0; ks < 2; ks++) {
      bf16x8 ah[4], al[4], bh[4], bl[4];
#pragma unroll
      for (int i = 0; i < 4; i++) {
        int row = wm * 64 + i * 16 + l15;
        int k8  = ks * 4 + quad;
        int ci  = k8 ^ (row & 7);
        ah[i] = ((const bf16x8*)AhiS)[row * 8 + ci];
        al[i] = ((const bf16x8*)AloS)[row * 8 + ci];
        int nrow = wn * 64 + i * 16 + l15;
        int cj   = k8 ^ (nrow & 7);
        bh[i] = ((const bf16x8*)BhiS)[nrow * 8 + cj];
        bl[i] = ((const bf16x8*)BloS)[nrow * 8 + cj];
      }
#pragma unroll
      for (int i = 0; i < 4; i++)
#pragma unroll
        for (int j = 0; j < 4; j++) {
          acc[i][j] = __builtin_amdgcn_mfma_f32_16x16x32_bf16(al[i], bh[j], acc[i][j], 0, 0, 0);
          acc[i][j] = __builtin_amdgcn_mfma_f32_16x16x32_bf16(ah[i], bl[j], acc[i][j], 0, 0, 0);
          acc[i][j] = __builtin_amdgcn_mfma_f32_16x16x32_bf16(ah[i], bh[j], acc[i][j], 0, 0, 0);
        }
    }
    __syncthreads();
  }

  float bv[4], scv[4], shv[4];
#pragma unroll
  for (int j = 0; j < 4; j++) {
    int col = bn + wn*64 + j*16 + l15;
    if (BIAS)    bv[j]  = bias[col];
    if (RESIDBN) { scv[j] = rsc[col]; shv[j] = rsh[col]; }
  }
  float sj[4] = {0.f,0.f,0.f,0.f}, qj[4] = {0.f,0.f,0.f,0.f};
#pragma unroll
  for (int i = 0; i < 4; i++) {
#pragma unroll
    for (int r = 0; r < 4; r++) {
      int row = bm + wm*64 + i*16 + quad*4 + r;
#pragma unroll
      for (int j = 0; j < 4; j++) {
        int col = bn + wn*64 + j*16 + l15;
        float v = acc[i][j][r];
        if (BIAS)    v += bv[j];
        if (RELU)    v = fmaxf(v, 0.f);
        if (RESIDBN) v += fmaf(residf[(size_t)row * Ntot + col], scv[j], shv[j]);
        if (OUTF32)  Cf[(size_t)row * Ntot + col] = v;
        if (OUTHL) {
          ushort hi, lo;
          split2(v, hi, lo);
          Chi[(size_t)row * Ntot + col] = hi;
          Clo[(size_t)row * Ntot + col] = lo;
        }
        if (STATS) { sj[j] += v; qj[j] = fmaf(v, v, qj[j]); }
      }
    }
  }
  if (STATS) {
#pragma unroll
    for (int j = 0; j < 4; j++) {
      sj[j] += __shfl_xor(sj[j], 16); sj[j] += __shfl_xor(sj[j], 32);
      qj[j] += __shfl_xor(qj[j], 16); qj[j] += __shfl_xor(qj[j], 32);
    }
    float* ssum = (float*)AhiS;     // safe: k-loop ended with barrier
    float* ssq  = ssum + 128;
    if (t < 128) { ssum[t] = 0.f; ssq[t] = 0.f; }
    __syncthreads();
    if (quad == 0) {
#pragma unroll
      for (int j = 0; j < 4; j++) {
        int col = wn*64 + j*16 + l15;
        atomicAdd(&ssum[col], sj[j]);
        atomicAdd(&ssq[col],  qj[j]);
      }
    }
    __syncthreads();
    if (t < 128) {
      psum[blockIdx.y * 128 + t] = ssum[t];
      psq [blockIdx.y * 128 + t] = ssq[t];
    }
  }
}

// ---------------- fused attention: chunked online softmax, packed f32x2 math ----------------
__global__ __launch_bounds__(256) void attn_kernel(const float* __restrict__ qkv,
    ushort* __restrict__ Ohi, ushort* __restrict__ Olo)
{
  __shared__ __align__(16) float Ks[N_][KD_];
  __shared__ __align__(16) float Vs[N_][KD_];
  const int b  = blockIdx.x >> 3;
  const int hh = blockIdx.x & 7;
  const int t  = threadIdx.x;
  const float* basep = qkv + (size_t)b * N_ * 384;
  for (int i = t; i < N_ * 8; i += 256) {
    int n = i >> 3, q4 = i & 7;
    if (q4 < 4)
      ((float4*)&Ks[n][0])[q4]     = *(const float4*)(basep + n*384 + 128 + hh*16 + q4*4);
    else
      ((float4*)&Vs[n][0])[q4 - 4] = *(const float4*)(basep + n*384 + 256 + hh*16 + (q4-4)*4);
  }
  __syncthreads();
  if (t < N_) {
    union F4 { float4 f4; f32x2 h[2]; };
    f32x2 q2[8];
#pragma unroll
    for (int j4 = 0; j4 < 4; j4++) {
      F4 v4; v4.f4 = *(const float4*)(basep + t*384 + hh*16 + j4*4);
      q2[j4*2+0] = v4.h[0] * 0.25f;     // fold 1/sqrt(KD) into q
      q2[j4*2+1] = v4.h[1] * 0.25f;
    }
    float m = -1e30f, l = 0.f;
    f32x2 o2[8] = {};
    for (int c0 = 0; c0 < N_; c0 += 40) {
      float s[40];
      float cmax = -1e30f;
#pragma unroll
      for (int j = 0; j < 40; j++) {
        const F4* kr = (const F4*)&Ks[c0 + j][0];
        F4 k0 = kr[0], k1 = kr[1], k2 = kr[2], k3 = kr[3];
        f32x2 a2 = q2[0] * k0.h[0];
        a2 = __builtin_elementwise_fma(q2[1], k0.h[1], a2);
        a2 = __builtin_elementwise_fma(q2[2], k1.h[0], a2);
        a2 = __builtin_elementwise_fma(q2[3], k1.h[1], a2);
        a2 = __builtin_elementwise_fma(q2[4], k2.h[0], a2);
        a2 = __builtin_elementwise_fma(q2[5], k2.h[1], a2);
        a2 = __builtin_elementwise_fma(q2[6], k3.h[0], a2);
        a2 = __builtin_elementwise_fma(q2[7], k3.h[1], a2);
        float a = a2[0] + a2[1];
        s[j] = a;
        cmax = fmaxf(cmax, a);
      }
      float mn   = fmaxf(m, cmax);
      float corr = __expf(m - mn);
      l *= corr;
      f32x2 corr2 = { corr, corr };
#pragma unroll
      for (int e = 0; e < 8; e++) o2[e] *= corr2;
#pragma unroll
      for (int j = 0; j < 40; j++) {
        float p = __expf(s[j] - mn);
        l += p;
        f32x2 p2 = { p, p };
        const F4* vr = (const F4*)&Vs[c0 + j][0];
        F4 v0 = vr[0], v1 = vr[1], v2 = vr[2], v3 = vr[3];
        o2[0] = __builtin_elementwise_fma(p2, v0.h[0], o2[0]);
        o2[1] = __builtin_elementwise_fma(p2, v0.h[1], o2[1]);
        o2[2] = __builtin_elementwise_fma(p2, v1.h[0], o2[2]);
        o2[3] = __builtin_elementwise_fma(p2, v1.h[1], o2[3]);
        o2[4] = __builtin_elementwise_fma(p2, v2.h[0], o2[4]);
        o2[5] = __builtin_elementwise_fma(p2, v2.h[1], o2[5]);
        o2[6] = __builtin_elementwise_fma(p2, v3.h[0], o2[6]);
        o2[7] = __builtin_elementwise_fma(p2, v3.h[1], o2[7]);
      }
      m = mn;
    }
    float inv = 1.f / l;
    f32x2 inv2 = { inv, inv };
    ushort hi[16], lo[16];
#pragma unroll
    for (int e = 0; e < 8; e++) {
      f32x2 ov = o2[e] * inv2;
      split2(ov[0], hi[e*2+0], lo[e*2+0]);
      split2(ov[1], hi[e*2+1], lo[e*2+1]);
    }
    size_t obase = ((size_t)(b * N_ + t)) * 128 + hh * 16;
    uint4 ph0, ph1, pl0, pl1;
    ph0.x = (uint)hi[0]  | ((uint)hi[1]  << 16); ph0.y = (uint)hi[2]  | ((uint)hi[3]  << 16);
    ph0.z = (uint)hi[4]  | ((uint)hi[5]  << 16); ph0.w = (uint)hi[6]  | ((uint)hi[7]  << 16);
    ph1.x = (uint)hi[8]  | ((uint)hi[9]  << 16); ph1.y = (uint)hi[10] | ((uint)hi[11] << 16);
    ph1.z = (uint)hi[12] | ((uint)hi[13] << 16); ph1.w = (uint)hi[14] | ((uint)hi[15] << 16);
    pl0.x = (uint)lo[0]  | ((uint)lo[1]  << 16); pl0.y = (uint)lo[2]  | ((uint)lo[3]  << 16);
    pl0.z = (uint)lo[4]  | ((uint)lo[5]  << 16); pl0.w = (uint)lo[6]  | ((uint)lo[7]  << 16);
    pl1.x = (uint)lo[8]  | ((uint)lo[9]  << 16); pl1.y = (uint)lo[10] | ((uint)lo[11] << 16);
    pl1.z = (uint)lo[12] | ((uint)lo[13] << 16); pl1.w = (uint)lo[14] | ((uint)lo[15] << 16);
    ((uint4*)(Ohi + obase))[0] = ph0;
    ((uint4*)(Ohi + obase))[1] = ph1;
    ((uint4*)(Olo + obase))[0] = pl0;
    ((uint4*)(Olo + obase))[1] = pl1;
  }
}

// ---------------- BN finalize -> folded scale/shift ----------------
__global__ __launch_bounds__(128) void bn_finalize(const float* __restrict__ psum,
    const float* __restrict__ psq, const float* __restrict__ g,
    const float* __restrict__ bta, float* __restrict__ scale, float* __restrict__ shift)
{
  int c = threadIdx.x;
  float s = 0.f, q = 0.f;
  for (int i = 0; i < 400; i++) { s += psum[i*128 + c]; q += psq[i*128 + c]; }
  const float invM = 1.f / 51200.f;
  float m  = s * invM;
  float v  = fmaf(q, invM, -m * m);
  float r  = rsqrtf(v + 1e-5f);
  float sc = r * g[c];
  scale[c] = sc;
  shift[c] = fmaf(-m, sc, bta[c]);
}

// ---------------- final BN apply (in place, fp32) ----------------
__global__ __launch_bounds__(256) void bn_apply_final(float* __restrict__ hp,
    const float* __restrict__ scale, const float* __restrict__ shift)
{
  int i4 = blockIdx.x * 256 + threadIdx.x;   // ROWS*32 exact
  int c4 = i4 & 31;
  float4 v  = ((float4*)hp)[i4];
  float4 sc = ((const float4*)scale)[c4];
  float4 sh = ((const float4*)shift)[c4];
  v.x = fmaf(v.x, sc.x, sh.x);
  v.y = fmaf(v.y, sc.y, sh.y);
  v.z = fmaf(v.z, sc.z, sh.z);
  v.w = fmaf(v.w, sc.w, sh.w);
  ((float4*)hp)[i4] = v;
}

// ---------------- final mean over N ----------------
__global__ __launch_bounds__(128) void mean_kernel(const float* __restrict__ h,
                                                   float* __restrict__ out)
{
  int b = blockIdx.x, d = threadIdx.x;
  const float* p = h + (size_t)b * N_ * D_ + d;
  float s = 0.f;
  for (int n = 0; n < N_; n++) s += p[n * D_];
  out[b * D_ + d] = s * (1.f / N_);
}

extern "C" void kernel_launch(void* const* d_in, const int* in_sizes, int n_in,
                              void* d_out, int out_size, void* d_ws, size_t ws_size,
                              hipStream_t stream)
{
  const float* x    = (const float*)d_in[0];
  const float* Wemb = (const float*)d_in[1];
  const float* bemb = (const float*)d_in[2];
  const float* Wq   = (const float*)d_in[3];
  const float* Wk   = (const float*)d_in[4];
  const float* Wv   = (const float*)d_in[5];
  const float* Wo   = (const float*)d_in[6];
  const float* bn1g = (const float*)d_in[7];
  const float* bn1b = (const float*)d_in[8];
  const float* W1   = (const float*)d_in[9];
  const float* b1   = (const float*)d_in[10];
  const float* W2   = (const float*)d_in[11];
  const float* b2   = (const float*)d_in[12];
  const float* bn2g = (const float*)d_in[13];
  const float* bn2b = (const float*)d_in[14];
  float* out = (float*)d_out;

  // rolling pre-BN residual state hp lives in d_out[0:BND]
  float* hp = out;

  char* wsb = (char*)d_ws;
  ushort* h_hi  = (ushort*)wsb;                     // 13,107,200 B
  ushort* h_lo  = (ushort*)(wsb + 13107200);        // 13,107,200 B
  char*   phase = wsb + 26214400;                   // 104,857,600 B union
  float*  qkv   = (float*)phase;                    //   attn: 78,643,200 B fp32
  ushort* hd_hi = (ushort*)(phase + 78643200);      //   attn: 13,107,200 B
  ushort* hd_lo = (ushort*)(phase + 91750400);      //   attn: 13,107,200 B
  ushort* hid_hi = (ushort*)phase;                  //   ffn: 52,428,800 B
  ushort* hid_lo = (ushort*)(phase + 52428800);     //   ffn: 52,428,800 B
  char*   wp    = wsb + 131072000;
  ushort* woT_hi  = (ushort*)wp;                    // 98,304 B
  ushort* woT_lo  = (ushort*)(wp + 98304);          // 98,304 B
  ushort* w2T_hi  = (ushort*)(wp + 196608);         // 393,216 B
  ushort* w2T_lo  = (ushort*)(wp + 589824);         // 393,216 B
  ushort* fqkv_hi = (ushort*)(wp + 983040);         // 98,304 B
  ushort* fqkv_lo = (ushort*)(wp + 1081344);        // 98,304 B
  ushort* fw1_hi  = (ushort*)(wp + 1179648);        // 131,072 B
  ushort* fw1_lo  = (ushort*)(wp + 1310720);        // 131,072 B
  float*  fqkv_b  = (float*)(wp + 1441792);         // 1,536 B
  float*  fw1_b   = (float*)(wp + 1443328);         // 2,048 B
  float*  psum    = (float*)(wp + 1445376);         // 204,800 B
  float*  psq     = (float*)(wp + 1650176);         // 204,800 B
  float*  sc_a    = (float*)(wp + 1854976);
  float*  sh_a    = (float*)(wp + 1855488);
  float*  sc_b    = (float*)(wp + 1856000);
  float*  sh_b    = (float*)(wp + 1856512);

  embed_kernel<<<6400, 256, 0, stream>>>(x, Wemb, bemb, hp, h_hi, h_lo);
  t_wo<<<192, 256, 0, stream>>>(Wo, woT_hi, woT_lo);
  t_w2<<<768, 256, 0, stream>>>(W2, w2T_hi, w2T_lo);
  init_scales<<<1, 128, 0, stream>>>(sc_b, sh_b);

  for (int l = 0; l < L_; l++) {
    // fold BN(prev layer / identity) into QKV weights
    fold_qkv<<<1, 384, 0, stream>>>(Wq + l*16384, Wk + l*16384, Wv + l*16384,
                                    sc_b, sh_b, fqkv_hi, fqkv_lo, fqkv_b);
    // QKV projection (consumes pre-BN h hi/lo + folded weights) -> qkv fp32
    gemm_mfma<128, true, false, false, true, false, false><<<dim3(3, 400), 256, 0, stream>>>(
        h_hi, h_lo, fqkv_hi, fqkv_lo, fqkv_b, nullptr, nullptr, nullptr,
        qkv, nullptr, nullptr, nullptr, nullptr, 384);
    // attention -> heads hi/lo
    attn_kernel<<<B_ * H_, 256, 0, stream>>>(qkv, hd_hi, hd_lo);
    // out-proj + BN-folded residual -> hp (h1_pre) fp32 + hi/lo + BN1 stats
    gemm_mfma<128, false, false, true, true, true, true><<<dim3(1, 400), 256, 0, stream>>>(
        hd_hi, hd_lo, woT_hi + l*16384, woT_lo + l*16384, nullptr, hp, sc_b, sh_b,
        hp, h_hi, h_lo, psum, psq, 128);
    bn_finalize<<<1, 128, 0, stream>>>(psum, psq, bn1g + l*128, bn1b + l*128, sc_a, sh_a);
    // fold BN1 into W1
    fold_w1<<<2, 256, 0, stream>>>(W1 + l*65536, b1 + l*512, sc_a, sh_a, fw1_hi, fw1_lo, fw1_b);
    // FFN1 + folded bias + relu -> hidden hi/lo
    gemm_mfma<128, true, true, false, false, true, false><<<dim3(4, 400), 256, 0, stream>>>(
        h_hi, h_lo, fw1_hi, fw1_lo, fw1_b, nullptr, nullptr, nullptr,
        nullptr, hid_hi, hid_lo, nullptr, nullptr, 512);
    // FFN2 + bias + BN1-folded residual -> hp (h2_pre) fp32 + hi/lo + BN2 stats
    gemm_mfma<512, true, false, true, true, true, true><<<dim3(1, 400), 256, 0, stream>>>(
        hid_hi, hid_lo, w2T_hi + l*65536, w2T_lo + l*65536, b2 + l*128, hp, sc_a, sh_a,
        hp, h_hi, h_lo, psum, psq, 128);
    bn_finalize<<<1, 128, 0, stream>>>(psum, psq, bn2g + l*128, bn2b + l*128, sc_b, sh_b);
  }

  bn_apply_final<<<6400, 256, 0, stream>>>(hp, sc_b, sh_b);
  mean_kernel<<<B_, 128, 0, stream>>>(hp, out + BND);
}

// Round 8
// 905.408 us; speedup vs baseline: 1.3488x; 1.3488x over previous
//
#include <hip/hip_runtime.h>
#include <math.h>

#define B_ 256
#define N_ 200
#define D_ 128
#define H_ 8
#define KD_ 16
#define L_ 3
#define FF_ 512
#define ROWS (B_*N_)          // 51200
#define BND (ROWS*D_)         // 6,553,600

typedef __bf16 bf16x8 __attribute__((ext_vector_type(8)));
typedef float f32x4 __attribute__((ext_vector_type(4)));

__device__ __forceinline__ ushort f2bf(float f) {
  union { float f; unsigned u; } v; v.f = f;
  unsigned r = v.u + 0x7fffu + ((v.u >> 16) & 1u);
  return (ushort)(r >> 16);
}
__device__ __forceinline__ float bf2f(ushort h) {
  union { unsigned u; float f; } v; v.u = ((unsigned)h) << 16; return v.f;
}
__device__ __forceinline__ void split2(float f, ushort& hi, ushort& lo) {
  hi = f2bf(f);
  lo = f2bf(f - bf2f(hi));
}

// ---------------- embed: h = x @ Wemb + bemb -> hp fp32 + hi/lo bf16 ----------------
__global__ __launch_bounds__(256) void embed_kernel(const float* __restrict__ x,
    const float* __restrict__ Wemb, const float* __restrict__ bemb,
    float* __restrict__ hp, ushort* __restrict__ hhi, ushort* __restrict__ hlo)
{
  int i4 = blockIdx.x * 256 + threadIdx.x;   // ROWS*32 float4s
  int r  = i4 >> 5, c4 = i4 & 31;
  float x0 = x[2*r], x1 = x[2*r + 1];
  const float4 w0 = ((const float4*)Wemb)[c4];
  const float4 w1 = ((const float4*)Wemb)[32 + c4];
  const float4 bb = ((const float4*)bemb)[c4];
  float o[4];
  o[0] = fmaf(x0, w0.x, fmaf(x1, w1.x, bb.x));
  o[1] = fmaf(x0, w0.y, fmaf(x1, w1.y, bb.y));
  o[2] = fmaf(x0, w0.z, fmaf(x1, w1.z, bb.z));
  o[3] = fmaf(x0, w0.w, fmaf(x1, w1.w, bb.w));
  float4 of = { o[0], o[1], o[2], o[3] };
  ((float4*)hp)[i4] = of;
  ushort hi[4], lo[4];
#pragma unroll
  for (int k = 0; k < 4; k++) split2(o[k], hi[k], lo[k]);
  uint2 ph, pl;
  ph.x = (uint)hi[0] | ((uint)hi[1] << 16);
  ph.y = (uint)hi[2] | ((uint)hi[3] << 16);
  pl.x = (uint)lo[0] | ((uint)lo[1] << 16);
  pl.y = (uint)lo[2] | ((uint)lo[3] << 16);
  ((uint2*)hhi)[i4] = ph;
  ((uint2*)hlo)[i4] = pl;
}

// ------------- static weight transposes (Wo, W2) -> bf16 hi/lo [N][K] -------------
__global__ __launch_bounds__(256) void t_wo(const float* __restrict__ Wo,
    ushort* __restrict__ dhi, ushort* __restrict__ dlo)
{
  int i = blockIdx.x * 256 + threadIdx.x;     // L*128*128 = 49152 exact
  int l = i / 16384, r = i % 16384;
  int n = r >> 7, k = r & 127;
  int hh = k >> 4, kd = k & 15;
  float w = Wo[l*16384 + hh*2048 + kd*128 + n];
  split2(w, dhi[i], dlo[i]);
}
__global__ __launch_bounds__(256) void t_w2(const float* __restrict__ W2,
    ushort* __restrict__ dhi, ushort* __restrict__ dlo)
{
  int i = blockIdx.x * 256 + threadIdx.x;     // L*128*512 = 196608 exact
  int l = i / 65536, r = i % 65536;
  int d = r >> 9, f = r & 511;
  float w = W2[l*65536 + f*128 + d];
  split2(w, dhi[i], dlo[i]);
}

// ------------- init BN-fold state to identity -------------
__global__ __launch_bounds__(128) void init_scales(float* __restrict__ sc, float* __restrict__ sh)
{
  int c = threadIdx.x;
  sc[c] = 1.f;
  sh[c] = 0.f;
}

// ------------- fold BN into QKV weights (PARALLEL: block=n-row, thread=k) -------------
// W'[n][k] = sc[k]*W[k][n]; b'[n] = sum_k sh[k]*W[k][n]
__global__ __launch_bounds__(128) void fold_qkv(const float* __restrict__ Wq,
    const float* __restrict__ Wk, const float* __restrict__ Wv,
    const float* __restrict__ sc, const float* __restrict__ sh,
    ushort* __restrict__ whi, ushort* __restrict__ wlo, float* __restrict__ bout)
{
  __shared__ float wsum[2];
  int n = blockIdx.x;                     // 0..383
  int k = threadIdx.x;                    // 0..127
  int which = n >> 7, hh = (n >> 4) & 7, kd = n & 15;
  const float* src = (which == 0) ? Wq : (which == 1) ? Wk : Wv;
  float w = src[hh*2048 + k*16 + kd];
  split2(w * sc[k], whi[n*128 + k], wlo[n*128 + k]);   // coalesced writes over k
  float p = sh[k] * w;
#pragma unroll
  for (int d = 1; d < 64; d <<= 1) p += __shfl_xor(p, d);
  if ((k & 63) == 0) wsum[k >> 6] = p;
  __syncthreads();
  if (k == 0) bout[n] = wsum[0] + wsum[1];
}

// ------------- fold BN into W1 (PARALLEL: block=f-row, thread=k) -------------
__global__ __launch_bounds__(128) void fold_w1(const float* __restrict__ W1,
    const float* __restrict__ b1, const float* __restrict__ sc, const float* __restrict__ sh,
    ushort* __restrict__ whi, ushort* __restrict__ wlo, float* __restrict__ bout)
{
  __shared__ float wsum[2];
  int f = blockIdx.x;                     // 0..511
  int k = threadIdx.x;                    // 0..127
  float w = W1[k*512 + f];
  split2(w * sc[k], whi[f*128 + k], wlo[f*128 + k]);
  float p = sh[k] * w;
#pragma unroll
  for (int d = 1; d < 64; d <<= 1) p += __shfl_xor(p, d);
  if ((k & 63) == 0) wsum[k >> 6] = p;
  __syncthreads();
  if (k == 0) bout[f] = b1[f] + wsum[0] + wsum[1];
}

// ---------------- split-bf16 MFMA GEMM: BK=64 XOR-swizzle body + BN-fold epilogue ----------------
template<int K, bool BIAS, bool RELU, bool RESIDBN, bool OUTF32, bool OUTHL, bool STATS>
__global__ __launch_bounds__(256, 2) void gemm_mfma(
    const ushort* __restrict__ Ahi, const ushort* __restrict__ Alo,
    const ushort* __restrict__ Whi, const ushort* __restrict__ Wlo,
    const float* __restrict__ bias,
    const float* __restrict__ residf, const float* __restrict__ rsc, const float* __restrict__ rsh,
    float* __restrict__ Cf, ushort* __restrict__ Chi, ushort* __restrict__ Clo,
    float* __restrict__ psum, float* __restrict__ psq, int Ntot)
{
  __shared__ ushort AhiS[128*64];
  __shared__ ushort AloS[128*64];
  __shared__ ushort BhiS[128*64];
  __shared__ ushort BloS[128*64];
  const int t    = threadIdx.x;
  const int bm   = blockIdx.y * 128;
  const int bn   = blockIdx.x * 128;
  const int lane = t & 63;
  const int w    = t >> 6, wm = w >> 1, wn = w & 1;
  const int quad = lane >> 4, l15 = lane & 15;

  f32x4 acc[4][4];
#pragma unroll
  for (int i = 0; i < 4; i++)
#pragma unroll
    for (int j = 0; j < 4; j++) acc[i][j] = (f32x4){0.f, 0.f, 0.f, 0.f};

  const ushort* AhiB = Ahi + (size_t)bm * K;
  const ushort* AloB = Alo + (size_t)bm * K;
  const ushort* BhiB = Whi + (size_t)bn * K;
  const ushort* BloB = Wlo + (size_t)bn * K;

  for (int k0 = 0; k0 < K; k0 += 64) {
#pragma unroll
    for (int i = 0; i < 4; i++) {
      int idx = i * 256 + t;
      int row = idx >> 3, c = idx & 7;
      int k8  = c ^ (row & 7);
      size_t off = (size_t)row * K + k0 + k8 * 8;
      ((uint4*)AhiS)[idx] = *(const uint4*)(AhiB + off);
      ((uint4*)AloS)[idx] = *(const uint4*)(AloB + off);
      ((uint4*)BhiS)[idx] = *(const uint4*)(BhiB + off);
      ((uint4*)BloS)[idx] = *(const uint4*)(BloB + off);
    }
    __syncthreads();
#pragma unroll
    for (int ks = 0; ks < 2; ks++) {
      bf16x8 ah[4], al[4], bh[4], bl[4];
#pragma unroll
      for (int i = 0; i < 4; i++) {
        int row = wm * 64 + i * 16 + l15;
        int k8  = ks * 4 + quad;
        int ci  = k8 ^ (row & 7);
        ah[i] = ((const bf16x8*)AhiS)[row * 8 + ci];
        al[i] = ((const bf16x8*)AloS)[row * 8 + ci];
        int nrow = wn * 64 + i * 16 + l15;
        int cj   = k8 ^ (nrow & 7);
        bh[i] = ((const bf16x8*)BhiS)[nrow * 8 + cj];
        bl[i] = ((const bf16x8*)BloS)[nrow * 8 + cj];
      }
#pragma unroll
      for (int i = 0; i < 4; i++)
#pragma unroll
        for (int j = 0; j < 4; j++) {
          acc[i][j] = __builtin_amdgcn_mfma_f32_16x16x32_bf16(al[i], bh[j], acc[i][j], 0, 0, 0);
          acc[i][j] = __builtin_amdgcn_mfma_f32_16x16x32_bf16(ah[i], bl[j], acc[i][j], 0, 0, 0);
          acc[i][j] = __builtin_amdgcn_mfma_f32_16x16x32_bf16(ah[i], bh[j], acc[i][j], 0, 0, 0);
        }
    }
    __syncthreads();
  }

  float bv[4], scv[4], shv[4];
#pragma unroll
  for (int j = 0; j < 4; j++) {
    int col = bn + wn*64 + j*16 + l15;
    if (BIAS)    bv[j]  = bias[col];
    if (RESIDBN) { scv[j] = rsc[col]; shv[j] = rsh[col]; }
  }
  float sj[4] = {0.f,0.f,0.f,0.f}, qj[4] = {0.f,0.f,0.f,0.f};
#pragma unroll
  for (int i = 0; i < 4; i++) {
#pragma unroll
    for (int r = 0; r < 4; r++) {
      int row = bm + wm*64 + i*16 + quad*4 + r;
#pragma unroll
      for (int j = 0; j < 4; j++) {
        int col = bn + wn*64 + j*16 + l15;
        float v = acc[i][j][r];
        if (BIAS)    v += bv[j];
        if (RELU)    v = fmaxf(v, 0.f);
        if (RESIDBN) v += fmaf(residf[(size_t)row * Ntot + col], scv[j], shv[j]);
        if (OUTF32)  Cf[(size_t)row * Ntot + col] = v;
        if (OUTHL) {
          ushort hi, lo;
          split2(v, hi, lo);
          Chi[(size_t)row * Ntot + col] = hi;
          Clo[(size_t)row * Ntot + col] = lo;
        }
        if (STATS) { sj[j] += v; qj[j] = fmaf(v, v, qj[j]); }
      }
    }
  }
  if (STATS) {
#pragma unroll
    for (int j = 0; j < 4; j++) {
      sj[j] += __shfl_xor(sj[j], 16); sj[j] += __shfl_xor(sj[j], 32);
      qj[j] += __shfl_xor(qj[j], 16); qj[j] += __shfl_xor(qj[j], 32);
    }
    float* ssum = (float*)AhiS;     // safe: k-loop ended with barrier
    float* ssq  = ssum + 128;
    if (t < 128) { ssum[t] = 0.f; ssq[t] = 0.f; }
    __syncthreads();
    if (quad == 0) {
#pragma unroll
      for (int j = 0; j < 4; j++) {
        int col = wn*64 + j*16 + l15;
        atomicAdd(&ssum[col], sj[j]);
        atomicAdd(&ssq[col],  qj[j]);
      }
    }
    __syncthreads();
    if (t < 128) {
      psum[blockIdx.y * 128 + t] = ssum[t];
      psq [blockIdx.y * 128 + t] = ssq[t];
    }
  }
}

// ---------------- fused attention (proven R3/R5 scalar version) ----------------
__global__ __launch_bounds__(256) void attn_kernel(const float* __restrict__ qkv,
    ushort* __restrict__ Ohi, ushort* __restrict__ Olo)
{
  __shared__ __align__(16) float Ks[N_][KD_];
  __shared__ __align__(16) float Vs[N_][KD_];
  const int b  = blockIdx.x >> 3;
  const int hh = blockIdx.x & 7;
  const int t  = threadIdx.x;
  const float* basep = qkv + (size_t)b * N_ * 384;
  for (int i = t; i < N_ * 8; i += 256) {
    int n = i >> 3, q4 = i & 7;
    if (q4 < 4)
      ((float4*)&Ks[n][0])[q4]     = *(const float4*)(basep + n*384 + 128 + hh*16 + q4*4);
    else
      ((float4*)&Vs[n][0])[q4 - 4] = *(const float4*)(basep + n*384 + 256 + hh*16 + (q4-4)*4);
  }
  __syncthreads();
  if (t < N_) {
    float q[KD_];
#pragma unroll
    for (int j4 = 0; j4 < 4; j4++) {
      float4 v4 = *(const float4*)(basep + t*384 + hh*16 + j4*4);
      q[j4*4+0] = v4.x; q[j4*4+1] = v4.y; q[j4*4+2] = v4.z; q[j4*4+3] = v4.w;
    }
    float m = -1e30f, l = 0.f;
    float o[KD_] = {0.f};
    for (int c0 = 0; c0 < N_; c0 += 40) {
      float s[40];
      float cmax = -1e30f;
#pragma unroll
      for (int j = 0; j < 40; j++) {
        const float4* kr = (const float4*)&Ks[c0 + j][0];
        float4 k0 = kr[0], k1 = kr[1], k2 = kr[2], k3 = kr[3];
        float a = 0.f;
        a = fmaf(q[0],  k0.x, a); a = fmaf(q[1],  k0.y, a);
        a = fmaf(q[2],  k0.z, a); a = fmaf(q[3],  k0.w, a);
        a = fmaf(q[4],  k1.x, a); a = fmaf(q[5],  k1.y, a);
        a = fmaf(q[6],  k1.z, a); a = fmaf(q[7],  k1.w, a);
        a = fmaf(q[8],  k2.x, a); a = fmaf(q[9],  k2.y, a);
        a = fmaf(q[10], k2.z, a); a = fmaf(q[11], k2.w, a);
        a = fmaf(q[12], k3.x, a); a = fmaf(q[13], k3.y, a);
        a = fmaf(q[14], k3.z, a); a = fmaf(q[15], k3.w, a);
        a *= 0.25f;
        s[j] = a;
        cmax = fmaxf(cmax, a);
      }
      float mn   = fmaxf(m, cmax);
      float corr = __expf(m - mn);
      l *= corr;
#pragma unroll
      for (int kk = 0; kk < KD_; kk++) o[kk] *= corr;
#pragma unroll
      for (int j = 0; j < 40; j++) {
        float p = __expf(s[j] - mn);
        l += p;
        const float4* vr = (const float4*)&Vs[c0 + j][0];
        float4 v0 = vr[0], v1 = vr[1], v2 = vr[2], v3 = vr[3];
        o[0]  = fmaf(p, v0.x, o[0]);  o[1]  = fmaf(p, v0.y, o[1]);
        o[2]  = fmaf(p, v0.z, o[2]);  o[3]  = fmaf(p, v0.w, o[3]);
        o[4]  = fmaf(p, v1.x, o[4]);  o[5]  = fmaf(p, v1.y, o[5]);
        o[6]  = fmaf(p, v1.z, o[6]);  o[7]  = fmaf(p, v1.w, o[7]);
        o[8]  = fmaf(p, v2.x, o[8]);  o[9]  = fmaf(p, v2.y, o[9]);
        o[10] = fmaf(p, v2.z, o[10]); o[11] = fmaf(p, v2.w, o[11]);
        o[12] = fmaf(p, v3.x, o[12]); o[13] = fmaf(p, v3.y, o[13]);
        o[14] = fmaf(p, v3.z, o[14]); o[15] = fmaf(p, v3.w, o[15]);
      }
      m = mn;
    }
    float inv = 1.f / l;
    ushort hi[16], lo[16];
#pragma unroll
    for (int kk = 0; kk < KD_; kk++) split2(o[kk] * inv, hi[kk], lo[kk]);
    size_t obase = ((size_t)(b * N_ + t)) * 128 + hh * 16;
    uint4 ph0, ph1, pl0, pl1;
    ph0.x = (uint)hi[0]  | ((uint)hi[1]  << 16); ph0.y = (uint)hi[2]  | ((uint)hi[3]  << 16);
    ph0.z = (uint)hi[4]  | ((uint)hi[5]  << 16); ph0.w = (uint)hi[6]  | ((uint)hi[7]  << 16);
    ph1.x = (uint)hi[8]  | ((uint)hi[9]  << 16); ph1.y = (uint)hi[10] | ((uint)hi[11] << 16);
    ph1.z = (uint)hi[12] | ((uint)hi[13] << 16); ph1.w = (uint)hi[14] | ((uint)hi[15] << 16);
    pl0.x = (uint)lo[0]  | ((uint)lo[1]  << 16); pl0.y = (uint)lo[2]  | ((uint)lo[3]  << 16);
    pl0.z = (uint)lo[4]  | ((uint)lo[5]  << 16); pl0.w = (uint)lo[6]  | ((uint)lo[7]  << 16);
    pl1.x = (uint)lo[8]  | ((uint)lo[9]  << 16); pl1.y = (uint)lo[10] | ((uint)lo[11] << 16);
    pl1.z = (uint)lo[12] | ((uint)lo[13] << 16); pl1.w = (uint)lo[14] | ((uint)lo[15] << 16);
    ((uint4*)(Ohi + obase))[0] = ph0;
    ((uint4*)(Ohi + obase))[1] = ph1;
    ((uint4*)(Olo + obase))[0] = pl0;
    ((uint4*)(Olo + obase))[1] = pl1;
  }
}

// ---------------- BN finalize -> folded scale/shift ----------------
__global__ __launch_bounds__(128) void bn_finalize(const float* __restrict__ psum,
    const float* __restrict__ psq, const float* __restrict__ g,
    const float* __restrict__ bta, float* __restrict__ scale, float* __restrict__ shift)
{
  int c = threadIdx.x;
  float s = 0.f, q = 0.f;
  for (int i = 0; i < 400; i++) { s += psum[i*128 + c]; q += psq[i*128 + c]; }
  const float invM = 1.f / 51200.f;
  float m  = s * invM;
  float v  = fmaf(q, invM, -m * m);
  float r  = rsqrtf(v + 1e-5f);
  float sc = r * g[c];
  scale[c] = sc;
  shift[c] = fmaf(-m, sc, bta[c]);
}

// ---------------- final BN apply (in place, fp32) ----------------
__global__ __launch_bounds__(256) void bn_apply_final(float* __restrict__ hp,
    const float* __restrict__ scale, const float* __restrict__ shift)
{
  int i4 = blockIdx.x * 256 + threadIdx.x;   // ROWS*32 exact
  int c4 = i4 & 31;
  float4 v  = ((float4*)hp)[i4];
  float4 sc = ((const float4*)scale)[c4];
  float4 sh = ((const float4*)shift)[c4];
  v.x = fmaf(v.x, sc.x, sh.x);
  v.y = fmaf(v.y, sc.y, sh.y);
  v.z = fmaf(v.z, sc.z, sh.z);
  v.w = fmaf(v.w, sc.w, sh.w);
  ((float4*)hp)[i4] = v;
}

// ---------------- final mean over N ----------------
__global__ __launch_bounds__(128) void mean_kernel(const float* __restrict__ h,
                                                   float* __restrict__ out)
{
  int b = blockIdx.x, d = threadIdx.x;
  const float* p = h + (size_t)b * N_ * D_ + d;
  float s = 0.f;
  for (int n = 0; n < N_; n++) s += p[n * D_];
  out[b * D_ + d] = s * (1.f / N_);
}

extern "C" void kernel_launch(void* const* d_in, const int* in_sizes, int n_in,
                              void* d_out, int out_size, void* d_ws, size_t ws_size,
                              hipStream_t stream)
{
  const float* x    = (const float*)d_in[0];
  const float* Wemb = (const float*)d_in[1];
  const float* bemb = (const float*)d_in[2];
  const float* Wq   = (const float*)d_in[3];
  const float* Wk   = (const float*)d_in[4];
  const float* Wv   = (const float*)d_in[5];
  const float* Wo   = (const float*)d_in[6];
  const float* bn1g = (const float*)d_in[7];
  const float* bn1b = (const float*)d_in[8];
  const float* W1   = (const float*)d_in[9];
  const float* b1   = (const float*)d_in[10];
  const float* W2   = (const float*)d_in[11];
  const float* b2   = (const float*)d_in[12];
  const float* bn2g = (const float*)d_in[13];
  const float* bn2b = (const float*)d_in[14];
  float* out = (float*)d_out;

  // rolling pre-BN residual state hp lives in d_out[0:BND]
  float* hp = out;

  char* wsb = (char*)d_ws;
  ushort* h_hi  = (ushort*)wsb;                     // 13,107,200 B
  ushort* h_lo  = (ushort*)(wsb + 13107200);        // 13,107,200 B
  char*   phase = wsb + 26214400;                   // 104,857,600 B union
  float*  qkv   = (float*)phase;                    //   attn: 78,643,200 B fp32
  ushort* hd_hi = (ushort*)(phase + 78643200);      //   attn: 13,107,200 B
  ushort* hd_lo = (ushort*)(phase + 91750400);      //   attn: 13,107,200 B
  ushort* hid_hi = (ushort*)phase;                  //   ffn: 52,428,800 B
  ushort* hid_lo = (ushort*)(phase + 52428800);     //   ffn: 52,428,800 B
  char*   wp    = wsb + 131072000;
  ushort* woT_hi  = (ushort*)wp;                    // 98,304 B
  ushort* woT_lo  = (ushort*)(wp + 98304);          // 98,304 B
  ushort* w2T_hi  = (ushort*)(wp + 196608);         // 393,216 B
  ushort* w2T_lo  = (ushort*)(wp + 589824);         // 393,216 B
  ushort* fqkv_hi = (ushort*)(wp + 983040);         // 98,304 B
  ushort* fqkv_lo = (ushort*)(wp + 1081344);        // 98,304 B
  ushort* fw1_hi  = (ushort*)(wp + 1179648);        // 131,072 B
  ushort* fw1_lo  = (ushort*)(wp + 1310720);        // 131,072 B
  float*  fqkv_b  = (float*)(wp + 1441792);         // 1,536 B
  float*  fw1_b   = (float*)(wp + 1443328);         // 2,048 B
  float*  psum    = (float*)(wp + 1445376);         // 204,800 B
  float*  psq     = (float*)(wp + 1650176);         // 204,800 B
  float*  sc_a    = (float*)(wp + 1854976);
  float*  sh_a    = (float*)(wp + 1855488);
  float*  sc_b    = (float*)(wp + 1856000);
  float*  sh_b    = (float*)(wp + 1856512);

  embed_kernel<<<6400, 256, 0, stream>>>(x, Wemb, bemb, hp, h_hi, h_lo);
  t_wo<<<192, 256, 0, stream>>>(Wo, woT_hi, woT_lo);
  t_w2<<<768, 256, 0, stream>>>(W2, w2T_hi, w2T_lo);
  init_scales<<<1, 128, 0, stream>>>(sc_b, sh_b);

  for (int l = 0; l < L_; l++) {
    // fold BN(prev layer / identity) into QKV weights (parallel, coalesced)
    fold_qkv<<<384, 128, 0, stream>>>(Wq + l*16384, Wk + l*16384, Wv + l*16384,
                                      sc_b, sh_b, fqkv_hi, fqkv_lo, fqkv_b);
    // QKV projection (consumes pre-BN h hi/lo + folded weights) -> qkv fp32
    gemm_mfma<128, true, false, false, true, false, false><<<dim3(3, 400), 256, 0, stream>>>(
        h_hi, h_lo, fqkv_hi, fqkv_lo, fqkv_b, nullptr, nullptr, nullptr,
        qkv, nullptr, nullptr, nullptr, nullptr, 384);
    // attention -> heads hi/lo
    attn_kernel<<<B_ * H_, 256, 0, stream>>>(qkv, hd_hi, hd_lo);
    // out-proj + BN-folded residual -> hp (h1_pre) fp32 + hi/lo + BN1 stats
    gemm_mfma<128, false, false, true, true, true, true><<<dim3(1, 400), 256, 0, stream>>>(
        hd_hi, hd_lo, woT_hi + l*16384, woT_lo + l*16384, nullptr, hp, sc_b, sh_b,
        hp, h_hi, h_lo, psum, psq, 128);
    bn_finalize<<<1, 128, 0, stream>>>(psum, psq, bn1g + l*128, bn1b + l*128, sc_a, sh_a);
    // fold BN1 into W1 (parallel, coalesced)
    fold_w1<<<512, 128, 0, stream>>>(W1 + l*65536, b1 + l*512, sc_a, sh_a, fw1_hi, fw1_lo, fw1_b);
    // FFN1 + folded bias + relu -> hidden hi/lo
    gemm_mfma<128, true, true, false, false, true, false><<<dim3(4, 400), 256, 0, stream>>>(
        h_hi, h_lo, fw1_hi, fw1_lo, fw1_b, nullptr, nullptr, nullptr,
        nullptr, hid_hi, hid_lo, nullptr, nullptr, 512);
    // FFN2 + bias + BN1-folded residual -> hp (h2_pre) fp32 + hi/lo + BN2 stats
    gemm_mfma<512, true, false, true, true, true, true><<<dim3(1, 400), 256, 0, stream>>>(
        hid_hi, hid_lo, w2T_hi + l*65536, w2T_lo + l*65536, b2 + l*128, hp, sc_a, sh_a,
        hp, h_hi, h_lo, psum, psq, 128);
    bn_finalize<<<1, 128, 0, stream>>>(psum, psq, bn2g + l*128, bn2b + l*128, sc_b, sh_b);
  }

  bn_apply_final<<<6400, 256, 0, stream>>>(hp, sc_b, sh_b);
  mean_kernel<<<B_, 128, 0, stream>>>(hp, out + BND);
}